// Round 1
// baseline (1821.794 us; speedup 1.0000x reference)
//
#include <hip/hip_runtime.h>

#define BLOCK 1024   // 16 waves of 64
#define NQ 15

__device__ __forceinline__ float2 cmul(float2 a, float2 b){
  return make_float2(a.x*b.x - a.y*b.y, a.x*b.y + a.y*b.x);
}
__device__ __forceinline__ float2 cmadd2(float2 u, float2 a, float2 v, float2 b){
  // u*a + v*b (complex)
  return make_float2(u.x*a.x - u.y*a.y + v.x*b.x - v.y*b.y,
                     u.x*a.y + u.y*a.x + v.x*b.y + v.y*b.x);
}

// ---- rotation on a local bit BL (0..4): in-register pairs ----
template<int BL>
__device__ __forceinline__ void rot_local(float2* a, const float* u){
  float2 u00 = make_float2(u[0],u[1]), u01 = make_float2(u[2],u[3]);
  float2 u10 = make_float2(u[4],u[5]), u11 = make_float2(u[6],u[7]);
  #pragma unroll
  for (int k0 = 0; k0 < 32; k0++){
    if (k0 & (1<<BL)) continue;
    const int k1 = k0 | (1<<BL);
    float2 a0 = a[k0], a1 = a[k1];
    a[k0] = cmadd2(u00, a0, u01, a1);
    a[k1] = cmadd2(u10, a0, u11, a1);
  }
}

// ---- rotation on a lane bit LB (0..5): wave shuffle ----
template<int LB>
__device__ __forceinline__ void rot_lane(float2* a, const float* u, int lane){
  const int bit = (lane >> LB) & 1;
  float2 u00 = make_float2(u[0],u[1]), u01 = make_float2(u[2],u[3]);
  float2 u10 = make_float2(u[4],u[5]), u11 = make_float2(u[6],u[7]);
  float2 ua = bit ? u11 : u00;   // coefficient of own amp
  float2 ub = bit ? u10 : u01;   // coefficient of partner amp
  #pragma unroll
  for (int k = 0; k < 32; k++){
    float2 p;
    p.x = __shfl_xor(a[k].x, 1<<LB, 64);
    p.y = __shfl_xor(a[k].y, 1<<LB, 64);
    a[k] = cmadd2(ua, a[k], ub, p);
  }
}

// ---- rotation on a wave bit WB (0..3): LDS exchange, chunks of 8 ----
template<int WB>
__device__ __forceinline__ void rot_wave(float2* a, const float* u, int t, float2* xbuf){
  const int partner = t ^ (64 << WB);
  const int bit = (t >> (6 + WB)) & 1;
  float2 u00 = make_float2(u[0],u[1]), u01 = make_float2(u[2],u[3]);
  float2 u10 = make_float2(u[4],u[5]), u11 = make_float2(u[6],u[7]);
  float2 ua = bit ? u11 : u00;
  float2 ub = bit ? u10 : u01;
  #pragma unroll
  for (int c = 0; c < 4; c++){
    __syncthreads();                 // previous chunk's reads (or prior gate) done
    #pragma unroll
    for (int j = 0; j < 8; j++) xbuf[j*BLOCK + t] = a[c*8 + j];
    __syncthreads();
    #pragma unroll
    for (int j = 0; j < 8; j++){
      float2 p = xbuf[j*BLOCK + partner];
      a[c*8 + j] = cmadd2(ua, a[c*8 + j], ub, p);
    }
  }
}

// ---- CNOT, both bits local: conditional in-register swap ----
template<int BC, int BT>
__device__ __forceinline__ void cnot_local(float2* a){
  #pragma unroll
  for (int k = 0; k < 32; k++){
    if ((k & (1<<BC)) && !(k & (1<<BT))){
      float2 tmp = a[k]; a[k] = a[k | (1<<BT)]; a[k | (1<<BT)] = tmp;
    }
  }
}

// ---- CNOT, control lane bit CLB, target local bit BT ----
template<int CLB, int BT>
__device__ __forceinline__ void cnot_lanec_localt(float2* a, int lane){
  if ((lane >> CLB) & 1){
    #pragma unroll
    for (int k = 0; k < 32; k++){
      if (!(k & (1<<BT))){
        float2 tmp = a[k]; a[k] = a[k | (1<<BT)]; a[k | (1<<BT)] = tmp;
      }
    }
  }
}

// ---- CNOT, target = lane bit (shfl mask M), control = uniform-per-thread bool ----
template<int M>
__device__ __forceinline__ void cnot_shfl(float2* a, bool ctrl){
  #pragma unroll
  for (int k = 0; k < 32; k++){
    float2 p;
    p.x = __shfl_xor(a[k].x, M, 64);
    p.y = __shfl_xor(a[k].y, M, 64);
    if (ctrl) a[k] = p;
  }
}

// ---- CNOT, target = wave bit WB, control = uniform-per-thread bool ----
template<int WB>
__device__ __forceinline__ void cnot_wave(float2* a, bool ctrl, int t, float2* xbuf){
  const int partner = t ^ (64 << WB);
  #pragma unroll
  for (int c = 0; c < 4; c++){
    __syncthreads();
    #pragma unroll
    for (int j = 0; j < 8; j++) xbuf[j*BLOCK + t] = a[c*8 + j];
    __syncthreads();
    #pragma unroll
    for (int j = 0; j < 8; j++){
      float2 p = xbuf[j*BLOCK + partner];
      if (ctrl) a[c*8 + j] = p;
    }
  }
}

// ---- CNOT(14,0): control local bit0 (odd k), target wave bit3 (partner t^512) ----
__device__ __forceinline__ void cnot_q14(float2* a, int t, float2* xbuf){
  const int partner = t ^ 512;
  #pragma unroll
  for (int c = 0; c < 2; c++){
    __syncthreads();
    #pragma unroll
    for (int j = 0; j < 8; j++) xbuf[j*BLOCK + t] = a[(c*8 + j)*2 + 1];
    __syncthreads();
    #pragma unroll
    for (int j = 0; j < 8; j++) a[(c*8 + j)*2 + 1] = xbuf[j*BLOCK + partner];
  }
}

__global__ __launch_bounds__(BLOCK, 1)
void qdarts_kernel(const float* __restrict__ x,     // [64,15]
                   const float* __restrict__ P,     // [4,15,1,4]
                   const float* __restrict__ Q,     // [4,15,4,3]
                   const float* __restrict__ rot,   // [60]
                   const float* __restrict__ gn,    // [4,15,3]
                   float* __restrict__ out)         // [64,4]
{
  __shared__ float2 xbuf[8 * BLOCK];   // 64 KB exchange buffer
  __shared__ float  umat[60 * 8];      // 60 gate matrices (u00r,u00i,u01r,u01i,u10r,u10i,u11r,u11i)
  __shared__ float  part[16];

  const int t    = threadIdx.x;
  const int b    = blockIdx.x;
  const int lane = t & 63;
  const int wave = t >> 6;

  // ---- 1. gate selection + matrices (one thread per (layer,qubit)) ----
  if (t < 60){
    const int idx = t;                         // idx = l*15 + q
    const float* Pv = P  + idx*4;
    const float* Qv = Q  + idx*12;
    const float* gv = gn + idx*3;
    int g = 0; float best = -1e30f;
    #pragma unroll
    for (int j = 0; j < 3; j++){
      float lg = Pv[0]*Qv[0*3+j] + Pv[1]*Qv[1*3+j] + Pv[2]*Qv[2*3+j] + Pv[3]*Qv[3*3+j] + gv[j];
      if (lg > best){ best = lg; g = j; }      // first-max, same as jnp.argmax
    }
    const float half = rot[idx] * 0.5f;
    const float c = cosf(half), s = sinf(half);
    float m[8];
    if (g == 0){        // RX: [[c, -is],[-is, c]]
      m[0]=c; m[1]=0.f; m[2]=0.f; m[3]=-s; m[4]=0.f; m[5]=-s; m[6]=c; m[7]=0.f;
    } else if (g == 1){ // RY: [[c, -s],[s, c]]
      m[0]=c; m[1]=0.f; m[2]=-s; m[3]=0.f; m[4]=s; m[5]=0.f; m[6]=c; m[7]=0.f;
    } else {            // RZ: [[e^-iθ/2, 0],[0, e^iθ/2]]
      m[0]=c; m[1]=-s; m[2]=0.f; m[3]=0.f; m[4]=0.f; m[5]=0.f; m[6]=c; m[7]=s;
    }
    #pragma unroll
    for (int j = 0; j < 8; j++) umat[idx*8 + j] = m[j];
  }
  __syncthreads();

  // ---- 2. initial state = RY-encoded product state (real) ----
  // m = (t<<5)|k ; qubit q <-> m-bit (14-q). q in [0,9] <-> t-bit (9-q); q in [10,14] <-> k-bit (14-q).
  const float* xb = x + b*15;
  float hp = 1.f;
  #pragma unroll
  for (int q = 0; q < 10; q++){
    const float h = xb[q]*0.5f;
    hp *= ((t >> (9-q)) & 1) ? sinf(h) : cosf(h);
  }
  float lc[5], ls[5];
  #pragma unroll
  for (int j = 0; j < 5; j++){ const float h = xb[10+j]*0.5f; lc[j] = cosf(h); ls[j] = sinf(h); }
  float2 a[32];
  #pragma unroll
  for (int k = 0; k < 32; k++){
    float v = hp;
    #pragma unroll
    for (int j = 0; j < 5; j++) v *= ((k >> (4-j)) & 1) ? ls[j] : lc[j];
    a[k] = make_float2(v, 0.f);
  }

  // ---- 3. layers ----
  for (int l = 0; l < 4; l++){
    const float* U = umat + l*15*8;
    // rotations (commuting, reordered by locality). qubit q -> m-bit 14-q.
    rot_local<4>(a, U + 10*8);
    rot_local<3>(a, U + 11*8);
    rot_local<2>(a, U + 12*8);
    rot_local<1>(a, U + 13*8);
    rot_local<0>(a, U + 14*8);
    rot_lane<5>(a, U + 4*8, lane);
    rot_lane<4>(a, U + 5*8, lane);
    rot_lane<3>(a, U + 6*8, lane);
    rot_lane<2>(a, U + 7*8, lane);
    rot_lane<1>(a, U + 8*8, lane);
    rot_lane<0>(a, U + 9*8, lane);
    rot_wave<3>(a, U + 0*8, t, xbuf);
    rot_wave<2>(a, U + 1*8, t, xbuf);
    rot_wave<1>(a, U + 2*8, t, xbuf);
    rot_wave<0>(a, U + 3*8, t, xbuf);
    // CNOT ring, reference order q = 0..14 (adjacent CNOTs do not commute)
    cnot_wave<2>(a, (t >> 9) & 1, t, xbuf);   // q=0 : c=m14(w3), t=m13(w2)
    cnot_wave<1>(a, (t >> 8) & 1, t, xbuf);   // q=1 : c=m13(w2), t=m12(w1)
    cnot_wave<0>(a, (t >> 7) & 1, t, xbuf);   // q=2 : c=m12(w1), t=m11(w0)
    cnot_shfl<32>(a, (t >> 6) & 1);           // q=3 : c=m11(w0), t=m10(l5)
    cnot_shfl<16>(a, (lane >> 5) & 1);        // q=4 : c=m10(l5), t=m9(l4)
    cnot_shfl<8> (a, (lane >> 4) & 1);        // q=5
    cnot_shfl<4> (a, (lane >> 3) & 1);        // q=6
    cnot_shfl<2> (a, (lane >> 2) & 1);        // q=7
    cnot_shfl<1> (a, (lane >> 1) & 1);        // q=8 : c=m6(l1), t=m5(l0)
    cnot_lanec_localt<0,4>(a, lane);          // q=9 : c=m5(l0), t=m4(k4)
    cnot_local<4,3>(a);                       // q=10
    cnot_local<3,2>(a);                       // q=11
    cnot_local<2,1>(a);                       // q=12
    cnot_local<1,0>(a);                       // q=13
    cnot_q14(a, t, xbuf);                     // q=14: c=m0(k0), t=m14(w3)
  }

  // ---- 4. class probabilities: class = m>>13 = wave>>2 ----
  float s = 0.f;
  #pragma unroll
  for (int k = 0; k < 32; k++) s += a[k].x*a[k].x + a[k].y*a[k].y;
  #pragma unroll
  for (int off = 32; off > 0; off >>= 1) s += __shfl_down(s, off, 64);
  if (lane == 0) part[wave] = s;
  __syncthreads();
  if (t < 4){
    out[b*4 + t] = part[4*t] + part[4*t+1] + part[4*t+2] + part[4*t+3];
  }
}

extern "C" void kernel_launch(void* const* d_in, const int* in_sizes, int n_in,
                              void* d_out, int out_size, void* d_ws, size_t ws_size,
                              hipStream_t stream) {
  const float* x   = (const float*)d_in[0];
  const float* P   = (const float*)d_in[1];
  const float* Q   = (const float*)d_in[2];
  const float* rot = (const float*)d_in[3];
  const float* gn  = (const float*)d_in[4];
  float* out = (float*)d_out;
  hipLaunchKernelGGL(qdarts_kernel, dim3(64), dim3(BLOCK), 0, stream,
                     x, P, Q, rot, gn, out);
}

// Round 2
// 1764.664 us; speedup vs baseline: 1.0324x; 1.0324x over previous
//
#include <hip/hip_runtime.h>

#define BLOCK 1024   // 16 waves of 64
#define CHUNK 16     // amps per LDS exchange chunk (128 KB buffer)

__device__ __forceinline__ float2 cmadd2(float2 u, float2 a, float2 v, float2 b){
  // u*a + v*b (complex)
  return make_float2(u.x*a.x - u.y*a.y + v.x*b.x - v.y*b.y,
                     u.x*a.y + u.y*a.x + v.x*b.y + v.y*b.x);
}

// ---- rotation on a local bit BL (0..4): in-register pairs ----
template<int BL>
__device__ __forceinline__ void rot_local(float2* a, const float* u){
  float2 u00 = make_float2(u[0],u[1]), u01 = make_float2(u[2],u[3]);
  float2 u10 = make_float2(u[4],u[5]), u11 = make_float2(u[6],u[7]);
  #pragma unroll
  for (int k0 = 0; k0 < 32; k0++){
    if (k0 & (1<<BL)) continue;
    const int k1 = k0 | (1<<BL);
    float2 a0 = a[k0], a1 = a[k1];
    a[k0] = cmadd2(u00, a0, u01, a1);
    a[k1] = cmadd2(u10, a0, u11, a1);
  }
}

// ---- rotation on a lane bit LB (0..5): wave shuffle ----
template<int LB>
__device__ __forceinline__ void rot_lane(float2* a, const float* u, int lane){
  const int bit = (lane >> LB) & 1;
  float2 u00 = make_float2(u[0],u[1]), u01 = make_float2(u[2],u[3]);
  float2 u10 = make_float2(u[4],u[5]), u11 = make_float2(u[6],u[7]);
  float2 ua = bit ? u11 : u00;   // coefficient of own amp
  float2 ub = bit ? u10 : u01;   // coefficient of partner amp
  #pragma unroll
  for (int k = 0; k < 32; k++){
    float2 p;
    p.x = __shfl_xor(a[k].x, 1<<LB, 64);
    p.y = __shfl_xor(a[k].y, 1<<LB, 64);
    a[k] = cmadd2(ua, a[k], ub, p);
  }
}

// ---- rotation on a wave bit WB (0..3): LDS exchange, chunks of 16 ----
template<int WB>
__device__ __forceinline__ void rot_wave(float2* a, const float* u, int t, float2* xbuf){
  const int partner = t ^ (64 << WB);
  const int bit = (t >> (6 + WB)) & 1;
  float2 u00 = make_float2(u[0],u[1]), u01 = make_float2(u[2],u[3]);
  float2 u10 = make_float2(u[4],u[5]), u11 = make_float2(u[6],u[7]);
  float2 ua = bit ? u11 : u00;
  float2 ub = bit ? u10 : u01;
  #pragma unroll
  for (int c = 0; c < 2; c++){
    __syncthreads();                 // previous chunk's (or prior gate's) reads done
    #pragma unroll
    for (int j = 0; j < CHUNK; j++) xbuf[j*BLOCK + t] = a[c*CHUNK + j];
    __syncthreads();
    #pragma unroll
    for (int j = 0; j < CHUNK; j++){
      float2 p = xbuf[j*BLOCK + partner];
      a[c*CHUNK + j] = cmadd2(ua, a[c*CHUNK + j], ub, p);
    }
  }
}

// ---- CNOT, both bits local: conditional in-register swap ----
template<int BC, int BT>
__device__ __forceinline__ void cnot_local(float2* a){
  #pragma unroll
  for (int k = 0; k < 32; k++){
    if ((k & (1<<BC)) && !(k & (1<<BT))){
      float2 tmp = a[k]; a[k] = a[k | (1<<BT)]; a[k | (1<<BT)] = tmp;
    }
  }
}

// ---- CNOT, control lane bit CLB, target local bit BT ----
template<int CLB, int BT>
__device__ __forceinline__ void cnot_lanec_localt(float2* a, int lane){
  if ((lane >> CLB) & 1){
    #pragma unroll
    for (int k = 0; k < 32; k++){
      if (!(k & (1<<BT))){
        float2 tmp = a[k]; a[k] = a[k | (1<<BT)]; a[k | (1<<BT)] = tmp;
      }
    }
  }
}

// ---- CNOT, target = lane bit (shfl mask M), control = uniform-per-thread bool ----
template<int M>
__device__ __forceinline__ void cnot_shfl(float2* a, bool ctrl){
  #pragma unroll
  for (int k = 0; k < 32; k++){
    float2 p;
    p.x = __shfl_xor(a[k].x, M, 64);
    p.y = __shfl_xor(a[k].y, M, 64);
    if (ctrl) a[k] = p;
  }
}

// ---- CNOT, target = wave bit WB, control = uniform-per-thread bool ----
template<int WB>
__device__ __forceinline__ void cnot_wave(float2* a, bool ctrl, int t, float2* xbuf){
  const int partner = t ^ (64 << WB);
  #pragma unroll
  for (int c = 0; c < 2; c++){
    __syncthreads();
    #pragma unroll
    for (int j = 0; j < CHUNK; j++) xbuf[j*BLOCK + t] = a[c*CHUNK + j];
    __syncthreads();
    #pragma unroll
    for (int j = 0; j < CHUNK; j++){
      float2 p = xbuf[j*BLOCK + partner];
      if (ctrl) a[c*CHUNK + j] = p;
    }
  }
}

// ---- CNOT(14,0): control local bit0 (odd k), target wave bit3 (partner t^512) ----
// Only the 16 odd amps move -> exactly one chunk.
__device__ __forceinline__ void cnot_q14(float2* a, int t, float2* xbuf){
  const int partner = t ^ 512;
  __syncthreads();
  #pragma unroll
  for (int j = 0; j < CHUNK; j++) xbuf[j*BLOCK + t] = a[2*j + 1];
  __syncthreads();
  #pragma unroll
  for (int j = 0; j < CHUNK; j++) a[2*j + 1] = xbuf[j*BLOCK + partner];
}

__global__ __attribute__((amdgpu_flat_work_group_size(1024,1024), amdgpu_waves_per_eu(4,4)))
void qdarts_kernel(const float* __restrict__ x,     // [64,15]
                   const float* __restrict__ P,     // [4,15,1,4]
                   const float* __restrict__ Q,     // [4,15,4,3]
                   const float* __restrict__ rot,   // [60]
                   const float* __restrict__ gn,    // [4,15,3]
                   float* __restrict__ out)         // [64,4]
{
  __shared__ float2 xbuf[CHUNK * BLOCK];   // 128 KB exchange buffer (forces 1 block/CU)
  __shared__ float  umat[60 * 8];          // 60 gate matrices
  __shared__ float  part[16];

  const int t    = threadIdx.x;
  const int b    = blockIdx.x;
  const int lane = t & 63;
  const int wave = t >> 6;

  // ---- 1. gate selection + matrices (one thread per (layer,qubit)) ----
  if (t < 60){
    const int idx = t;                         // idx = l*15 + q
    const float* Pv = P  + idx*4;
    const float* Qv = Q  + idx*12;
    const float* gv = gn + idx*3;
    int g = 0; float best = -1e30f;
    #pragma unroll
    for (int j = 0; j < 3; j++){
      float lg = Pv[0]*Qv[0*3+j] + Pv[1]*Qv[1*3+j] + Pv[2]*Qv[2*3+j] + Pv[3]*Qv[3*3+j] + gv[j];
      if (lg > best){ best = lg; g = j; }      // first-max, same as jnp.argmax
    }
    const float half = rot[idx] * 0.5f;
    const float c = cosf(half), s = sinf(half);
    float m[8];
    if (g == 0){        // RX: [[c, -is],[-is, c]]
      m[0]=c; m[1]=0.f; m[2]=0.f; m[3]=-s; m[4]=0.f; m[5]=-s; m[6]=c; m[7]=0.f;
    } else if (g == 1){ // RY: [[c, -s],[s, c]]
      m[0]=c; m[1]=0.f; m[2]=-s; m[3]=0.f; m[4]=s; m[5]=0.f; m[6]=c; m[7]=0.f;
    } else {            // RZ: [[e^-iθ/2, 0],[0, e^iθ/2]]
      m[0]=c; m[1]=-s; m[2]=0.f; m[3]=0.f; m[4]=0.f; m[5]=0.f; m[6]=c; m[7]=s;
    }
    #pragma unroll
    for (int j = 0; j < 8; j++) umat[idx*8 + j] = m[j];
  }
  __syncthreads();

  // ---- 2. initial state = RY-encoded product state (real) ----
  // m = (t<<5)|k ; qubit q <-> m-bit (14-q). q in [0,9] <-> t-bit (9-q); q in [10,14] <-> k-bit (14-q).
  const float* xb = x + b*15;
  float hp = 1.f;
  #pragma unroll
  for (int q = 0; q < 10; q++){
    const float h = xb[q]*0.5f;
    hp *= ((t >> (9-q)) & 1) ? sinf(h) : cosf(h);
  }
  float lc[5], ls[5];
  #pragma unroll
  for (int j = 0; j < 5; j++){ const float h = xb[10+j]*0.5f; lc[j] = cosf(h); ls[j] = sinf(h); }
  float2 a[32];
  #pragma unroll
  for (int k = 0; k < 32; k++){
    float v = hp;
    #pragma unroll
    for (int j = 0; j < 5; j++) v *= ((k >> (4-j)) & 1) ? ls[j] : lc[j];
    a[k] = make_float2(v, 0.f);
  }

  // ---- 3. layers ----
  for (int l = 0; l < 4; l++){
    const float* U = umat + l*15*8;
    // rotations (commuting, reordered by locality). qubit q -> m-bit 14-q.
    rot_local<4>(a, U + 10*8);
    rot_local<3>(a, U + 11*8);
    rot_local<2>(a, U + 12*8);
    rot_local<1>(a, U + 13*8);
    rot_local<0>(a, U + 14*8);
    rot_lane<5>(a, U + 4*8, lane);
    rot_lane<4>(a, U + 5*8, lane);
    rot_lane<3>(a, U + 6*8, lane);
    rot_lane<2>(a, U + 7*8, lane);
    rot_lane<1>(a, U + 8*8, lane);
    rot_lane<0>(a, U + 9*8, lane);
    rot_wave<3>(a, U + 0*8, t, xbuf);
    rot_wave<2>(a, U + 1*8, t, xbuf);
    rot_wave<1>(a, U + 2*8, t, xbuf);
    rot_wave<0>(a, U + 3*8, t, xbuf);
    // CNOT ring, reference order q = 0..14 (adjacent CNOTs do not commute)
    cnot_wave<2>(a, (t >> 9) & 1, t, xbuf);   // q=0 : c=m14(w3), t=m13(w2)
    cnot_wave<1>(a, (t >> 8) & 1, t, xbuf);   // q=1 : c=m13(w2), t=m12(w1)
    cnot_wave<0>(a, (t >> 7) & 1, t, xbuf);   // q=2 : c=m12(w1), t=m11(w0)
    cnot_shfl<32>(a, (t >> 6) & 1);           // q=3 : c=m11(w0), t=m10(l5)
    cnot_shfl<16>(a, (lane >> 5) & 1);        // q=4 : c=m10(l5), t=m9(l4)
    cnot_shfl<8> (a, (lane >> 4) & 1);        // q=5
    cnot_shfl<4> (a, (lane >> 3) & 1);        // q=6
    cnot_shfl<2> (a, (lane >> 2) & 1);        // q=7
    cnot_shfl<1> (a, (lane >> 1) & 1);        // q=8 : c=m6(l1), t=m5(l0)
    cnot_lanec_localt<0,4>(a, lane);          // q=9 : c=m5(l0), t=m4(k4)
    cnot_local<4,3>(a);                       // q=10
    cnot_local<3,2>(a);                       // q=11
    cnot_local<2,1>(a);                       // q=12
    cnot_local<1,0>(a);                       // q=13
    cnot_q14(a, t, xbuf);                     // q=14: c=m0(k0), t=m14(w3)
  }

  // ---- 4. class probabilities: class = m>>13 = wave>>2 ----
  float s = 0.f;
  #pragma unroll
  for (int k = 0; k < 32; k++) s += a[k].x*a[k].x + a[k].y*a[k].y;
  #pragma unroll
  for (int off = 32; off > 0; off >>= 1) s += __shfl_down(s, off, 64);
  if (lane == 0) part[wave] = s;
  __syncthreads();
  if (t < 4){
    out[b*4 + t] = part[4*t] + part[4*t+1] + part[4*t+2] + part[4*t+3];
  }
}

extern "C" void kernel_launch(void* const* d_in, const int* in_sizes, int n_in,
                              void* d_out, int out_size, void* d_ws, size_t ws_size,
                              hipStream_t stream) {
  const float* x   = (const float*)d_in[0];
  const float* P   = (const float*)d_in[1];
  const float* Q   = (const float*)d_in[2];
  const float* rot = (const float*)d_in[3];
  const float* gn  = (const float*)d_in[4];
  float* out = (float*)d_out;
  hipLaunchKernelGGL(qdarts_kernel, dim3(64), dim3(BLOCK), 0, stream,
                     x, P, Q, rot, gn, out);
}

// Round 3
// 1459.588 us; speedup vs baseline: 1.2482x; 1.2090x over previous
//
#include <hip/hip_runtime.h>

#define BLOCK 1024   // 16 waves of 64
#define CHUNK 16     // amps per LDS exchange chunk (128 KB buffer)

// ---------- compile-time unroll machinery (no alloca, all indices constexpr) ----------
template<int I> struct IC { static constexpr int v = I; };

template<int N, int I = 0, class F>
__device__ __forceinline__ void sfor(F&& f){
  if constexpr (I < N){ f(IC<I>{}); sfor<N, I + 1>(static_cast<F&&>(f)); }
}

// ---------- state: 32 named float2 members, compile-time indexed ----------
struct St {
  float2 a0,a1,a2,a3,a4,a5,a6,a7,a8,a9,a10,a11,a12,a13,a14,a15,
         a16,a17,a18,a19,a20,a21,a22,a23,a24,a25,a26,a27,a28,a29,a30,a31;
  template<int I> __device__ __forceinline__ float2& g(){
    if constexpr (I==0) return a0;   else if constexpr (I==1) return a1;
    else if constexpr (I==2) return a2;   else if constexpr (I==3) return a3;
    else if constexpr (I==4) return a4;   else if constexpr (I==5) return a5;
    else if constexpr (I==6) return a6;   else if constexpr (I==7) return a7;
    else if constexpr (I==8) return a8;   else if constexpr (I==9) return a9;
    else if constexpr (I==10) return a10; else if constexpr (I==11) return a11;
    else if constexpr (I==12) return a12; else if constexpr (I==13) return a13;
    else if constexpr (I==14) return a14; else if constexpr (I==15) return a15;
    else if constexpr (I==16) return a16; else if constexpr (I==17) return a17;
    else if constexpr (I==18) return a18; else if constexpr (I==19) return a19;
    else if constexpr (I==20) return a20; else if constexpr (I==21) return a21;
    else if constexpr (I==22) return a22; else if constexpr (I==23) return a23;
    else if constexpr (I==24) return a24; else if constexpr (I==25) return a25;
    else if constexpr (I==26) return a26; else if constexpr (I==27) return a27;
    else if constexpr (I==28) return a28; else if constexpr (I==29) return a29;
    else if constexpr (I==30) return a30; else return a31;
  }
};

__device__ __forceinline__ float2 cmadd2(float2 u, float2 a, float2 v, float2 b){
  // u*a + v*b (complex)
  return make_float2(u.x*a.x - u.y*a.y + v.x*b.x - v.y*b.y,
                     u.x*a.y + u.y*a.x + v.x*b.y + v.y*b.x);
}

// ---- rotation on a local bit BL (0..4): in-register pairs ----
template<int BL>
__device__ __forceinline__ void rot_local(St& st, const float* u){
  float2 u00 = make_float2(u[0],u[1]), u01 = make_float2(u[2],u[3]);
  float2 u10 = make_float2(u[4],u[5]), u11 = make_float2(u[6],u[7]);
  sfor<32>([&](auto K){
    constexpr int k0 = decltype(K)::v;
    if constexpr (!(k0 & (1<<BL))){
      constexpr int k1 = k0 | (1<<BL);
      float2 x0 = st.g<k0>(), x1 = st.g<k1>();
      st.g<k0>() = cmadd2(u00, x0, u01, x1);
      st.g<k1>() = cmadd2(u10, x0, u11, x1);
    }
  });
}

// ---- rotation on a lane bit LB (0..5): wave shuffle ----
template<int LB>
__device__ __forceinline__ void rot_lane(St& st, const float* u, int lane){
  const int bit = (lane >> LB) & 1;
  float2 u00 = make_float2(u[0],u[1]), u01 = make_float2(u[2],u[3]);
  float2 u10 = make_float2(u[4],u[5]), u11 = make_float2(u[6],u[7]);
  float2 ua = bit ? u11 : u00;   // coefficient of own amp
  float2 ub = bit ? u10 : u01;   // coefficient of partner amp
  sfor<32>([&](auto K){
    constexpr int k = decltype(K)::v;
    float2& A = st.g<k>();
    float2 p;
    p.x = __shfl_xor(A.x, 1<<LB, 64);
    p.y = __shfl_xor(A.y, 1<<LB, 64);
    A = cmadd2(ua, A, ub, p);
  });
}

// ---- rotation on a wave bit WB (0..3): LDS exchange, chunks of 16 ----
template<int WB>
__device__ __forceinline__ void rot_wave(St& st, const float* u, int t, float2* xbuf){
  const int partner = t ^ (64 << WB);
  const int bit = (t >> (6 + WB)) & 1;
  float2 u00 = make_float2(u[0],u[1]), u01 = make_float2(u[2],u[3]);
  float2 u10 = make_float2(u[4],u[5]), u11 = make_float2(u[6],u[7]);
  float2 ua = bit ? u11 : u00;
  float2 ub = bit ? u10 : u01;
  sfor<2>([&](auto C){
    constexpr int c = decltype(C)::v;
    __syncthreads();                 // previous chunk's (or prior gate's) reads done
    sfor<CHUNK>([&](auto J){
      constexpr int j = decltype(J)::v;
      xbuf[j*BLOCK + t] = st.g<c*CHUNK + j>();
    });
    __syncthreads();
    sfor<CHUNK>([&](auto J){
      constexpr int j = decltype(J)::v;
      float2 p = xbuf[j*BLOCK + partner];
      float2& A = st.g<c*CHUNK + j>();
      A = cmadd2(ua, A, ub, p);
    });
  });
}

// ---- CNOT, both bits local: conditional in-register swap ----
template<int BC, int BT>
__device__ __forceinline__ void cnot_local(St& st){
  sfor<32>([&](auto K){
    constexpr int k = decltype(K)::v;
    if constexpr ((k & (1<<BC)) && !(k & (1<<BT))){
      constexpr int k1 = k | (1<<BT);
      float2 tmp = st.g<k>(); st.g<k>() = st.g<k1>(); st.g<k1>() = tmp;
    }
  });
}

// ---- CNOT, control lane bit CLB, target local bit BT ----
template<int CLB, int BT>
__device__ __forceinline__ void cnot_lanec_localt(St& st, int lane){
  const bool ctrl = (lane >> CLB) & 1;
  sfor<32>([&](auto K){
    constexpr int k = decltype(K)::v;
    if constexpr (!(k & (1<<BT))){
      constexpr int k1 = k | (1<<BT);
      float2 x0 = st.g<k>(), x1 = st.g<k1>();
      st.g<k>()  = ctrl ? x1 : x0;
      st.g<k1>() = ctrl ? x0 : x1;
    }
  });
}

// ---- CNOT, target = lane bit (shfl mask M), control = uniform-per-thread bool ----
template<int M>
__device__ __forceinline__ void cnot_shfl(St& st, bool ctrl){
  sfor<32>([&](auto K){
    constexpr int k = decltype(K)::v;
    float2& A = st.g<k>();
    float2 p;
    p.x = __shfl_xor(A.x, M, 64);
    p.y = __shfl_xor(A.y, M, 64);
    if (ctrl) A = p;
  });
}

// ---- CNOT, target = wave bit WB, control = uniform-per-thread bool ----
// Only ctrl==1 threads exchange (partner has same ctrl since control bit != WB bit).
template<int WB>
__device__ __forceinline__ void cnot_wave(St& st, bool ctrl, int t, float2* xbuf){
  const int partner = t ^ (64 << WB);
  sfor<2>([&](auto C){
    constexpr int c = decltype(C)::v;
    __syncthreads();
    if (ctrl){
      sfor<CHUNK>([&](auto J){
        constexpr int j = decltype(J)::v;
        xbuf[j*BLOCK + t] = st.g<c*CHUNK + j>();
      });
    }
    __syncthreads();
    if (ctrl){
      sfor<CHUNK>([&](auto J){
        constexpr int j = decltype(J)::v;
        st.g<c*CHUNK + j>() = xbuf[j*BLOCK + partner];
      });
    }
  });
}

// ---- CNOT(14,0): control local bit0 (odd k), target wave bit3 (partner t^512) ----
// Only the 16 odd amps move -> exactly one chunk.
__device__ __forceinline__ void cnot_q14(St& st, int t, float2* xbuf){
  const int partner = t ^ 512;
  __syncthreads();
  sfor<CHUNK>([&](auto J){
    constexpr int j = decltype(J)::v;
    xbuf[j*BLOCK + t] = st.g<2*j + 1>();
  });
  __syncthreads();
  sfor<CHUNK>([&](auto J){
    constexpr int j = decltype(J)::v;
    st.g<2*j + 1>() = xbuf[j*BLOCK + partner];
  });
}

__global__ __attribute__((amdgpu_flat_work_group_size(1024,1024), amdgpu_waves_per_eu(4,4)))
void qdarts_kernel(const float* __restrict__ x,     // [64,15]
                   const float* __restrict__ P,     // [4,15,1,4]
                   const float* __restrict__ Q,     // [4,15,4,3]
                   const float* __restrict__ rot,   // [60]
                   const float* __restrict__ gn,    // [4,15,3]
                   float* __restrict__ out)         // [64,4]
{
  __shared__ float2 xbuf[CHUNK * BLOCK];   // 128 KB exchange buffer
  __shared__ float  umat[60 * 8];          // 60 gate matrices
  __shared__ float  part[16];

  const int t    = threadIdx.x;
  const int b    = blockIdx.x;
  const int lane = t & 63;
  const int wave = t >> 6;

  // ---- 1. gate selection + matrices (one thread per (layer,qubit)) ----
  if (t < 60){
    const int idx = t;                         // idx = l*15 + q
    const float* Pv = P  + idx*4;
    const float* Qv = Q  + idx*12;
    const float* gv = gn + idx*3;
    int g = 0; float best = -1e30f;
    #pragma unroll
    for (int j = 0; j < 3; j++){
      float lg = Pv[0]*Qv[0*3+j] + Pv[1]*Qv[1*3+j] + Pv[2]*Qv[2*3+j] + Pv[3]*Qv[3*3+j] + gv[j];
      if (lg > best){ best = lg; g = j; }      // first-max, same as jnp.argmax
    }
    const float half = rot[idx] * 0.5f;
    const float c = cosf(half), s = sinf(half);
    float m0,m1,m2,m3,m4,m5,m6,m7;
    if (g == 0){        // RX: [[c, -is],[-is, c]]
      m0=c; m1=0.f; m2=0.f; m3=-s; m4=0.f; m5=-s; m6=c; m7=0.f;
    } else if (g == 1){ // RY: [[c, -s],[s, c]]
      m0=c; m1=0.f; m2=-s; m3=0.f; m4=s; m5=0.f; m6=c; m7=0.f;
    } else {            // RZ: [[e^-iθ/2, 0],[0, e^iθ/2]]
      m0=c; m1=-s; m2=0.f; m3=0.f; m4=0.f; m5=0.f; m6=c; m7=s;
    }
    umat[idx*8+0]=m0; umat[idx*8+1]=m1; umat[idx*8+2]=m2; umat[idx*8+3]=m3;
    umat[idx*8+4]=m4; umat[idx*8+5]=m5; umat[idx*8+6]=m6; umat[idx*8+7]=m7;
  }
  __syncthreads();

  // ---- 2. initial state = RY-encoded product state (real) ----
  // m = (t<<5)|k ; qubit q <-> m-bit (14-q). q in [0,9] <-> t-bit (9-q); q in [10,14] <-> k-bit (14-q).
  const float* xb = x + b*15;
  float hp = 1.f;
  #pragma unroll
  for (int q = 0; q < 10; q++){
    const float h = xb[q]*0.5f;
    hp *= ((t >> (9-q)) & 1) ? sinf(h) : cosf(h);
  }
  float lc0,lc1,lc2,lc3,lc4, ls0,ls1,ls2,ls3,ls4;
  { float h;
    h = xb[10]*0.5f; lc0 = cosf(h); ls0 = sinf(h);
    h = xb[11]*0.5f; lc1 = cosf(h); ls1 = sinf(h);
    h = xb[12]*0.5f; lc2 = cosf(h); ls2 = sinf(h);
    h = xb[13]*0.5f; lc3 = cosf(h); ls3 = sinf(h);
    h = xb[14]*0.5f; lc4 = cosf(h); ls4 = sinf(h);
  }
  St st;
  sfor<32>([&](auto K){
    constexpr int k = decltype(K)::v;
    float v = hp;
    v *= (k & 16) ? ls0 : lc0;
    v *= (k & 8)  ? ls1 : lc1;
    v *= (k & 4)  ? ls2 : lc2;
    v *= (k & 2)  ? ls3 : lc3;
    v *= (k & 1)  ? ls4 : lc4;
    st.g<k>() = make_float2(v, 0.f);
  });

  // ---- 3. layers ----
  for (int l = 0; l < 4; l++){
    const float* U = umat + l*15*8;
    // rotations (commuting, reordered by locality). qubit q -> m-bit 14-q.
    rot_local<4>(st, U + 10*8);
    rot_local<3>(st, U + 11*8);
    rot_local<2>(st, U + 12*8);
    rot_local<1>(st, U + 13*8);
    rot_local<0>(st, U + 14*8);
    rot_lane<5>(st, U + 4*8, lane);
    rot_lane<4>(st, U + 5*8, lane);
    rot_lane<3>(st, U + 6*8, lane);
    rot_lane<2>(st, U + 7*8, lane);
    rot_lane<1>(st, U + 8*8, lane);
    rot_lane<0>(st, U + 9*8, lane);
    rot_wave<3>(st, U + 0*8, t, xbuf);
    rot_wave<2>(st, U + 1*8, t, xbuf);
    rot_wave<1>(st, U + 2*8, t, xbuf);
    rot_wave<0>(st, U + 3*8, t, xbuf);
    // CNOT ring, reference order q = 0..14 (adjacent CNOTs do not commute)
    cnot_wave<2>(st, (t >> 9) & 1, t, xbuf);   // q=0 : c=m14(w3), t=m13(w2)
    cnot_wave<1>(st, (t >> 8) & 1, t, xbuf);   // q=1 : c=m13(w2), t=m12(w1)
    cnot_wave<0>(st, (t >> 7) & 1, t, xbuf);   // q=2 : c=m12(w1), t=m11(w0)
    cnot_shfl<32>(st, (t >> 6) & 1);           // q=3 : c=m11(w0), t=m10(l5)
    cnot_shfl<16>(st, (lane >> 5) & 1);        // q=4 : c=m10(l5), t=m9(l4)
    cnot_shfl<8> (st, (lane >> 4) & 1);        // q=5
    cnot_shfl<4> (st, (lane >> 3) & 1);        // q=6
    cnot_shfl<2> (st, (lane >> 2) & 1);        // q=7
    cnot_shfl<1> (st, (lane >> 1) & 1);        // q=8 : c=m6(l1), t=m5(l0)
    cnot_lanec_localt<0,4>(st, lane);          // q=9 : c=m5(l0), t=m4(k4)
    cnot_local<4,3>(st);                       // q=10
    cnot_local<3,2>(st);                       // q=11
    cnot_local<2,1>(st);                       // q=12
    cnot_local<1,0>(st);                       // q=13
    cnot_q14(st, t, xbuf);                     // q=14: c=m0(k0), t=m14(w3)
  }

  // ---- 4. class probabilities: class = m>>13 = wave>>2 ----
  float s = 0.f;
  sfor<32>([&](auto K){
    constexpr int k = decltype(K)::v;
    float2 A = st.g<k>();
    s += A.x*A.x + A.y*A.y;
  });
  #pragma unroll
  for (int off = 32; off > 0; off >>= 1) s += __shfl_down(s, off, 64);
  if (lane == 0) part[wave] = s;
  __syncthreads();
  if (t < 4){
    out[b*4 + t] = part[4*t] + part[4*t+1] + part[4*t+2] + part[4*t+3];
  }
}

extern "C" void kernel_launch(void* const* d_in, const int* in_sizes, int n_in,
                              void* d_out, int out_size, void* d_ws, size_t ws_size,
                              hipStream_t stream) {
  const float* x   = (const float*)d_in[0];
  const float* P   = (const float*)d_in[1];
  const float* Q   = (const float*)d_in[2];
  const float* rot = (const float*)d_in[3];
  const float* gn  = (const float*)d_in[4];
  float* out = (float*)d_out;
  hipLaunchKernelGGL(qdarts_kernel, dim3(64), dim3(BLOCK), 0, stream,
                     x, P, Q, rot, gn, out);
}